// Round 4
// baseline (40553.088 us; speedup 1.0000x reference)
//
#include <hip/hip_runtime.h>
#include <stdint.h>

// LSTM B=256 T=512 F=128 U=512 (Keras LSTMCell: gates i,f,c,o; unit_forget_bias)
//
// R4 = R3 with the c_last OUTPUT OFFSET BUG fixed.
// R2/R3 post-mortem: identical absmax 1.796875 on Output 2 in both rounds ->
// deterministic structural bug, not precision: c_last was stored at
// out + 67108864 + 262144 (2x131072) instead of out + 67108864 + 131072.
// The real c_last slot stayed zero -> error = max|c_ref| = 1.7969.
// Outputs 0/1 passed => MFMA layouts, barrier, h numerics verified on HW.
//
//  - 16 groups x 16 batches; group g = {bid : bid%16==g} (16 blocks, same XCD).
//  - Block = 16 batches x 32 units (x4 gates = 128 z-cols); 8 waves; wave = 16x16 tile.
//  - MFMA 16x16x32 bf16, fused K=640: z=[x_t|h]@[W;R]+b, weights in VGPRs (160/wave).
//  - Split-bf16 both sides: z = Ah*Bh + Ah*Bl + Al*Bh (3 chains; dropped Al*Bl ~1e-6).
//    Per-step z error ~1e-5 -> c integrates to ~5e-3 < 3.6e-2 threshold.
//  - h stored bf16 hi+lo (double-buffered), c fp32 in regs, gates fp32.
//  - Per-group device-scope atomic barrier per step.
// ws: counters | BTH | BTL | XTH | XTL | HBh | HBl  (~73 MB)

#define LSTM_B 256
#define LSTM_T 512
#define LSTM_F 128
#define LSTM_U 512

typedef float f32x4 __attribute__((ext_vector_type(4)));
typedef unsigned int u32x4 __attribute__((ext_vector_type(4)));
typedef unsigned short u16x4 __attribute__((ext_vector_type(4)));

#define MFMA16(acc, va, vb) \
  asm volatile("v_mfma_f32_16x16x32_bf16 %0, %1, %2, %0" : "+v"(acc) : "v"(va), "v"(vb))

__device__ __forceinline__ unsigned short f2bf(float f) {
  unsigned u = __builtin_bit_cast(unsigned, f);
  u += 0x7fffu + ((u >> 16) & 1u);   // round-to-nearest-even
  return (unsigned short)(u >> 16);
}

__device__ __forceinline__ float bf2f(unsigned short h) {
  unsigned u = ((unsigned)h) << 16;
  return __builtin_bit_cast(float, u);
}

__device__ __forceinline__ float tanh_fast(float x) {
  float ax = fabsf(x);
  float e = __expf(-2.f * ax);       // in (0,1], no overflow
  float t = (1.f - e) / (1.f + e);
  return copysignf(t, x);
}

__device__ __forceinline__ void group_barrier(unsigned* cnt, unsigned target) {
  __threadfence();      // release: h stores visible device-wide
  __syncthreads();
  if (threadIdx.x == 0) {
    __hip_atomic_fetch_add(cnt, 1u, __ATOMIC_RELEASE, __HIP_MEMORY_SCOPE_AGENT);
    while (__hip_atomic_load(cnt, __ATOMIC_ACQUIRE, __HIP_MEMORY_SCOPE_AGENT) < target) {}
  }
  __syncthreads();
  __threadfence();      // acquire before reading other blocks' h
}

// x [B][T][F] fp32 -> XTH/XTL [T][B][F] bf16 hi/lo ; 4 elems/thread
__global__ void xprep_kernel(const float* __restrict__ x,
                             unsigned short* __restrict__ xth,
                             unsigned short* __restrict__ xtl) {
  unsigned i4 = blockIdx.x * 256 + threadIdx.x;          // 0 .. 4194303
  const float* src = x + (size_t)i4 * 4;                 // coalesced read
  float a[4] = {src[0], src[1], src[2], src[3]};
  unsigned f4 = i4 & 31;
  unsigned t  = (i4 >> 5) & 511;
  unsigned b  = i4 >> 14;
  u16x4 oh, ol;
  #pragma unroll
  for (int j = 0; j < 4; ++j) {
    unsigned short hi = f2bf(a[j]);
    oh[j] = hi;
    ol[j] = f2bf(a[j] - bf2f(hi));
  }
  size_t off = (size_t)(t * 256 + b) * 128 + f4 * 4;
  *(u16x4*)(xth + off) = oh;
  *(u16x4*)(xtl + off) = ol;
}

// W [128][2048], R [512][2048] fp32 -> BTH/BTL [2048 cols][640 k] bf16 hi/lo
__global__ void wprep_kernel(const float* __restrict__ W, const float* __restrict__ R,
                             unsigned short* __restrict__ bth,
                             unsigned short* __restrict__ btl) {
  int col = blockIdx.x;      // 0..2047
  int k   = threadIdx.x;     // 0..639
  float v = (k < 128) ? W[(size_t)k * 2048 + col] : R[(size_t)(k - 128) * 2048 + col];
  unsigned short hi = f2bf(v);
  float lo = v - bf2f(hi);
  bth[(size_t)col * 640 + k] = hi;    // coalesced along k
  btl[(size_t)col * 640 + k] = f2bf(lo);
}

__global__ __launch_bounds__(512, 1) void lstm_kernel(
    const unsigned short* __restrict__ xth,
    const unsigned short* __restrict__ xtl,
    const unsigned short* __restrict__ bth,
    const unsigned short* __restrict__ btl,
    unsigned short* __restrict__ hbh,     // [2][256][512] bf16 hi
    unsigned short* __restrict__ hbl,     // [2][256][512] bf16 lo
    const float* __restrict__ bias,       // [2048]
    float* __restrict__ out,              // [B*T*U | B*U | B*U] fp32
    unsigned* __restrict__ counters)      // 16 groups, 256B apart
{
  const int tid = threadIdx.x;
  const int bid = blockIdx.x;
  const int g   = bid & 15;    // group (batch slice)
  const int idx = bid >> 4;    // unit slice within group
  const int u0  = idx << 5;    // 32 units per block

  const int lane = tid & 63;
  const int w    = tid >> 6;   // 8 waves
  const int l15  = lane & 15;
  const int kg   = lane >> 4;  // k-subgroup 0..3

  __shared__ float zs[8 * 16 * 16];   // [ntile][row(batch)][col(unit)] fp32

  // zero h buffer 0 (hi and lo), rows owned by this block (group-aligned)
  if (tid < 64) {
    u32x4 z = (u32x4){0u, 0u, 0u, 0u};
    ((u32x4*)(hbh + (size_t)(g * 16 + idx) * 512))[tid] = z;
    ((u32x4*)(hbl + (size_t)(g * 16 + idx) * 512))[tid] = z;
  }

  // ---- preload t-invariant B fragments: wave's 16 cols x K=640, hi+lo -> 160 VGPRs ----
  const int colb = (w >> 1) * 512 + u0 + ((w & 1) << 4) + l15;  // global z-col
  u32x4 bh[20], bl[20];
  {
    const unsigned short* bp = bth + (size_t)colb * 640 + (kg << 3);
    const unsigned short* lp = btl + (size_t)colb * 640 + (kg << 3);
    #pragma unroll
    for (int ks = 0; ks < 20; ++ks) {
      bh[ks] = *(const u32x4*)(bp + ks * 32);
      bl[ks] = *(const u32x4*)(lp + ks * 32);
    }
  }

  // ---- gate-phase constants: thread -> (batch-in-group bb, unit-in-block uu) ----
  const int bb = tid >> 5;           // 0..15
  const int uu = tid & 31;           // 0..31
  const int gb = g * 16 + bb;        // global batch
  const int ug = u0 + uu;            // global unit
  const float bi  = bias[ug];
  const float bf_ = bias[512 + ug];
  const float bg  = bias[1024 + ug];
  const float bo  = bias[1536 + ug];
  float c = 0.f;
  float* outp = out + (size_t)gb * (LSTM_T * LSTM_U) + ug;
  unsigned short* hwph = hbh + (size_t)gb * 512 + ug;
  unsigned short* hwpl = hbl + (size_t)gb * 512 + ug;

  // ---- GEMM A-side bases (row = group batch l15) ----
  const unsigned short* xbh = xth + (size_t)(g * 16 + l15) * 128 + (kg << 3);
  const unsigned short* xbl = xtl + (size_t)(g * 16 + l15) * 128 + (kg << 3);
  const unsigned short* hbhq = hbh + (size_t)(g * 16 + l15) * 512 + (kg << 3);
  const unsigned short* hblq = hbl + (size_t)(g * 16 + l15) * 512 + (kg << 3);

  unsigned* cnt = counters + (g << 6);
  unsigned target = 16;

  // prefetch x fragments for t=0
  u32x4 xah[4], xal[4];
  #pragma unroll
  for (int ks = 0; ks < 4; ++ks) {
    xah[ks] = *(const u32x4*)(xbh + ks * 32);
    xal[ks] = *(const u32x4*)(xbl + ks * 32);
  }

  group_barrier(cnt, target); target += 16;   // h0 zero visible group-wide

  for (int t = 0; t < LSTM_T; ++t) {
    f32x4 acc0 = {0.f, 0.f, 0.f, 0.f};   // Ah*Bh
    f32x4 acc1 = {0.f, 0.f, 0.f, 0.f};   // Ah*Bl
    f32x4 acc2 = {0.f, 0.f, 0.f, 0.f};   // Al*Bh
    asm volatile("s_nop 1" ::);          // VALU init -> MFMA srcC hazard pad
    // x part (K 0..127), prefetched
    #pragma unroll
    for (int ks = 0; ks < 4; ++ks) {
      MFMA16(acc0, xah[ks], bh[ks]);
      MFMA16(acc1, xah[ks], bl[ks]);
      MFMA16(acc2, xal[ks], bh[ks]);
    }
    // h part (K 128..639) from double-buffered split h
    const unsigned short* hrh = hbhq + ((t & 1) ? 131072 : 0);
    const unsigned short* hrl = hblq + ((t & 1) ? 131072 : 0);
    #pragma unroll
    for (int ks = 0; ks < 16; ++ks) {
      u32x4 ah = *(const u32x4*)(hrh + ks * 32);
      u32x4 al = *(const u32x4*)(hrl + ks * 32);
      MFMA16(acc0, ah, bh[4 + ks]);
      MFMA16(acc1, ah, bl[4 + ks]);
      MFMA16(acc2, al, bh[4 + ks]);
    }
    asm volatile("s_nop 7\ns_nop 7\ns_nop 7" ::);   // MFMA -> VALU read pad
    #pragma unroll
    for (int r = 0; r < 4; ++r)
      zs[((w * 16) + (kg << 2) + r) * 16 + l15] = acc0[r] + acc1[r] + acc2[r];
    __syncthreads();

    // ---- gate phase: thread owns (gb, ug); z tiles: ntile = gate*2 + (uu>>4) ----
    const int ci = uu >> 4;
    const int cj = uu & 15;
    float zi = zs[(((0 + ci) * 16) + bb) * 16 + cj] + bi;
    float zf = zs[(((2 + ci) * 16) + bb) * 16 + cj] + bf_;
    float zg = zs[(((4 + ci) * 16) + bb) * 16 + cj] + bg;
    float zo = zs[(((6 + ci) * 16) + bb) * 16 + cj] + bo;
    float iv = 1.f / (1.f + __expf(-zi));
    float fv = 1.f / (1.f + __expf(-zf));
    float gv = tanh_fast(zg);
    float ov = 1.f / (1.f + __expf(-zo));
    c = fv * c + iv * gv;
    float hn = ov * tanh_fast(c);
    unsigned short hh16 = f2bf(hn);
    unsigned short hl16 = f2bf(hn - bf2f(hh16));
    size_t hoff = (t & 1) ? 0 : 131072;       // write buffer (t+1)&1
    hwph[hoff] = hh16;
    hwpl[hoff] = hl16;
    __builtin_nontemporal_store(hn, outp + (size_t)t * 512);
    if (t == 511) {
      // h_last at [67108864, +131072), c_last at [67239936, +131072)
      __builtin_nontemporal_store(hn, out + 67108864 + (size_t)gb * 512 + ug);
      __builtin_nontemporal_store(c,  out + 67239936 + (size_t)gb * 512 + ug);
    }
    // prefetch next-step x fragments (independent of h; latency hides under spin)
    if (t < 511) {
      #pragma unroll
      for (int ks = 0; ks < 4; ++ks) {
        xah[ks] = *(const u32x4*)(xbh + (size_t)(t + 1) * 32768 + ks * 32);
        xal[ks] = *(const u32x4*)(xbl + (size_t)(t + 1) * 32768 + ks * 32);
      }
    }
    group_barrier(cnt, target); target += 16;
  }
}

extern "C" void kernel_launch(void* const* d_in, const int* in_sizes, int n_in,
                              void* d_out, int out_size, void* d_ws, size_t ws_size,
                              hipStream_t stream) {
  const float* x    = (const float*)d_in[0];
  const float* W    = (const float*)d_in[1];
  const float* R    = (const float*)d_in[2];
  const float* bias = (const float*)d_in[3];
  float* out = (float*)d_out;
  char* ws = (char*)d_ws;

  unsigned*       counters = (unsigned*)ws;                       // 4 KB
  unsigned short* BTH = (unsigned short*)(ws + 4096);             // 2,621,440 B
  unsigned short* BTL = (unsigned short*)(ws + 2625536);          // 2,621,440 B
  unsigned short* XTH = (unsigned short*)(ws + 5246976);          // 33,554,432 B
  unsigned short* XTL = (unsigned short*)(ws + 38801408);         // 33,554,432 B
  unsigned short* HBH = (unsigned short*)(ws + 72355840);         // 524,288 B
  unsigned short* HBL = (unsigned short*)(ws + 72880128);         // 524,288 B

  hipMemsetAsync(counters, 0, 4096, stream);
  hipLaunchKernelGGL(xprep_kernel, dim3(16384), dim3(256), 0, stream, x, XTH, XTL);
  hipLaunchKernelGGL(wprep_kernel, dim3(2048), dim3(640), 0, stream, W, R, BTH, BTL);

  const unsigned short* XTHc = XTH;
  const unsigned short* XTLc = XTL;
  const unsigned short* BTHc = BTH;
  const unsigned short* BTLc = BTL;
  void* args[9];
  args[0] = (void*)&XTHc;
  args[1] = (void*)&XTLc;
  args[2] = (void*)&BTHc;
  args[3] = (void*)&BTLc;
  args[4] = (void*)&HBH;
  args[5] = (void*)&HBL;
  args[6] = (void*)&bias;
  args[7] = (void*)&out;
  args[8] = (void*)&counters;
  hipLaunchCooperativeKernel((void*)lstm_kernel, dim3(256), dim3(512), args, 0, stream);
}

// Round 5
// 3263.184 us; speedup vs baseline: 12.4275x; 12.4275x over previous
//
#include <hip/hip_runtime.h>
#include <stdint.h>

// LSTM B=256 T=512 F=128 U=512 (Keras LSTMCell: gates i,f,c,o; unit_forget_bias)
//
// R5 = R4 restructured around the R4 counters (40.5ms, VGPR=128, MfmaUtil 1%):
//  1) R4's threadfence() = agent fence = per-step L2 writeback+invalidate -> all
//     locality destroyed. Replaced by explicit sc0/sc1 (system-coherent) h
//     exchange through L3 + relaxed device atomics. No fences at all.
//  2) R4's VGPR=128 shows the compiler rematerialized the weight loads in-loop
//     (no scratch traffic, but per-step L2/L3 reloads). Opaque asm "+v" on each
//     fragment defeats remat -> weights truly live in VGPRs (~160).
//  3) 8 waves redundantly re-loaded the same h tile (8x). Now one cooperative
//     32KB stage into XOR-swizzled LDS per block per step; MFMA A-frags via
//     ds_read_b128.
// Numerics (verified R4, absmax 3.9e-3): split-bf16 both sides,
// z = Ah*Bh + Ah*Bl + Al*Bh; h stored bf16 hi+lo; c fp32 in regs.
// ws: counters | BTH | BTL | XTH | XTL | HBh | HBl  (~73 MB)

#define LSTM_B 256
#define LSTM_T 512
#define LSTM_F 128
#define LSTM_U 512

typedef float f32x4 __attribute__((ext_vector_type(4)));
typedef unsigned int u32x4 __attribute__((ext_vector_type(4)));
typedef unsigned short u16x4 __attribute__((ext_vector_type(4)));

#define MFMA16(acc, va, vb) \
  asm volatile("v_mfma_f32_16x16x32_bf16 %0, %1, %2, %0" : "+v"(acc) : "v"(va), "v"(vb))

__device__ __forceinline__ unsigned short f2bf(float f) {
  unsigned u = __builtin_bit_cast(unsigned, f);
  u += 0x7fffu + ((u >> 16) & 1u);   // round-to-nearest-even
  return (unsigned short)(u >> 16);
}

__device__ __forceinline__ float bf2f(unsigned short h) {
  unsigned u = ((unsigned)h) << 16;
  return __builtin_bit_cast(float, u);
}

__device__ __forceinline__ float tanh_fast(float x) {
  float ax = fabsf(x);
  float e = __expf(-2.f * ax);       // in (0,1], no overflow
  float t = (1.f - e) / (1.f + e);
  return copysignf(t, x);
}

// x [B][T][F] fp32 -> XTH/XTL [T][B][F] bf16 hi/lo ; 4 elems/thread
__global__ void xprep_kernel(const float* __restrict__ x,
                             unsigned short* __restrict__ xth,
                             unsigned short* __restrict__ xtl) {
  unsigned i4 = blockIdx.x * 256 + threadIdx.x;          // 0 .. 4194303
  const float* src = x + (size_t)i4 * 4;                 // coalesced read
  float a[4] = {src[0], src[1], src[2], src[3]};
  unsigned f4 = i4 & 31;
  unsigned t  = (i4 >> 5) & 511;
  unsigned b  = i4 >> 14;
  u16x4 oh, ol;
  #pragma unroll
  for (int j = 0; j < 4; ++j) {
    unsigned short hi = f2bf(a[j]);
    oh[j] = hi;
    ol[j] = f2bf(a[j] - bf2f(hi));
  }
  size_t off = (size_t)(t * 256 + b) * 128 + f4 * 4;
  *(u16x4*)(xth + off) = oh;
  *(u16x4*)(xtl + off) = ol;
}

// W [128][2048], R [512][2048] fp32 -> BTH/BTL [2048 cols][640 k] bf16 hi/lo
__global__ void wprep_kernel(const float* __restrict__ W, const float* __restrict__ R,
                             unsigned short* __restrict__ bth,
                             unsigned short* __restrict__ btl) {
  int col = blockIdx.x;      // 0..2047
  int k   = threadIdx.x;     // 0..639
  float v = (k < 128) ? W[(size_t)k * 2048 + col] : R[(size_t)(k - 128) * 2048 + col];
  unsigned short hi = f2bf(v);
  float lo = v - bf2f(hi);
  bth[(size_t)col * 640 + k] = hi;    // coalesced along k
  btl[(size_t)col * 640 + k] = f2bf(lo);
}

__global__ __launch_bounds__(512, 2) void lstm_kernel(
    const unsigned short* __restrict__ xth,
    const unsigned short* __restrict__ xtl,
    const unsigned short* __restrict__ bth,
    const unsigned short* __restrict__ btl,
    unsigned short* __restrict__ hbh,     // [2][256][512] bf16 hi
    unsigned short* __restrict__ hbl,     // [2][256][512] bf16 lo
    const float* __restrict__ bias,       // [2048]
    float* __restrict__ out,              // [B*T*U | B*U | B*U] fp32
    unsigned* __restrict__ counters)      // 16 groups, 256B apart
{
  const int tid = threadIdx.x;
  const int bid = blockIdx.x;
  const int g   = bid & 15;    // group (batch slice)
  const int idx = bid >> 4;    // unit slice within group
  const int u0  = idx << 5;    // 32 units per block

  const int lane = tid & 63;
  const int w    = tid >> 6;   // 8 waves
  const int l15  = lane & 15;
  const int kg   = lane >> 4;  // k-subgroup 0..3

  __shared__ float zs[2048];       // z tiles [ntile][row][col]
  __shared__ char  hlds[32768];    // staged h tile: [hi 16KB | lo 16KB], XOR-swizzled

  // zero h buffer0: each block zeroes one group row (16 blocks/group cover 16 rows),
  // through the coherence point (sc0 sc1) so staged reads see it.
  if (tid < 64) {
    u32x4 zz = (u32x4){0u, 0u, 0u, 0u};
    char* p0 = (char*)hbh + (size_t)(g * 16 + idx) * 1024 + tid * 16;
    char* p1 = (char*)hbl + (size_t)(g * 16 + idx) * 1024 + tid * 16;
    asm volatile(
      "global_store_dwordx4 %0, %2, off sc0 sc1\n\t"
      "global_store_dwordx4 %1, %2, off sc0 sc1"
      :: "v"(p0), "v"(p1), "v"(zz) : "memory");
  }

  // ---- preload t-invariant B fragments (160 VGPRs), defeat rematerialization ----
  const int colb = (w >> 1) * 512 + u0 + ((w & 1) << 4) + l15;  // global z-col
  u32x4 bh[20], bl[20];
  {
    const unsigned short* bp = bth + (size_t)colb * 640 + (kg << 3);
    const unsigned short* lp = btl + (size_t)colb * 640 + (kg << 3);
    #pragma unroll
    for (int ks = 0; ks < 20; ++ks) {
      bh[ks] = *(const u32x4*)(bp + ks * 32);
      bl[ks] = *(const u32x4*)(lp + ks * 32);
    }
  }
  #pragma unroll
  for (int ks = 0; ks < 20; ++ks)
    asm volatile("" : "+v"(bh[ks]), "+v"(bl[ks]));   // opaque def: no remat

  // ---- gate-phase constants ----
  const int bb = tid >> 5;           // 0..15
  const int uu = tid & 31;           // 0..31
  const int gb = g * 16 + bb;        // global batch
  const int ug = u0 + uu;            // global unit
  const float bi  = bias[ug];
  const float bf_ = bias[512 + ug];
  const float bg  = bias[1024 + ug];
  const float bo  = bias[1536 + ug];
  float c = 0.f;
  float* outp = out + (size_t)gb * (LSTM_T * LSTM_U) + ug;
  unsigned short* hwph = hbh + (size_t)gb * 512 + ug;
  unsigned short* hwpl = hbl + (size_t)gb * 512 + ug;

  // ---- x A-side bases ----
  const unsigned short* xbh = xth + (size_t)(g * 16 + l15) * 128 + (kg << 3);
  const unsigned short* xbl = xtl + (size_t)(g * 16 + l15) * 128 + (kg << 3);

  // ---- h staging: 512 threads stage 32KB (hi 16K | lo 16K), 64B each ----
  const int st   = tid & 255;
  const int sel  = tid >> 8;                 // 0 = hi, 1 = lo
  const int slin = st * 64;                  // linear byte off within 16KB half
  const int smask = ((st >> 4) & 7) << 4;    // row XOR swizzle
  const char* gsb = (sel ? (const char*)hbl : (const char*)hbh)
                    + (size_t)g * 16384 + slin;
  char* lwp = hlds + sel * 16384;

  // ---- LDS read side (per lane): row l15, chunk col kg*16 + ks*64, swizzled ----
  const int rms = (l15 & 7) << 4;
  const char* rbh = hlds + l15 * 1024;

  unsigned* cnt = counters + (g << 6);
  unsigned target = 16;

  // prefetch x fragments for t=0
  u32x4 xah[4], xal[4];
  #pragma unroll
  for (int ks = 0; ks < 4; ++ks) {
    xah[ks] = *(const u32x4*)(xbh + ks * 32);
    xal[ks] = *(const u32x4*)(xbl + ks * 32);
  }

  // initial barrier: h0 zeros visible at coherence point
  asm volatile("s_waitcnt vmcnt(0)" ::: "memory");
  __syncthreads();
  if (tid == 0) {
    __hip_atomic_fetch_add(cnt, 1u, __ATOMIC_RELAXED, __HIP_MEMORY_SCOPE_AGENT);
    unsigned cur;
    do {
      asm volatile("global_load_dword %0, %1, off sc0 sc1\n\ts_waitcnt vmcnt(0)"
                   : "=v"(cur) : "v"(cnt) : "memory");
    } while (cur < target);
  }
  __syncthreads();
  target += 16;

  for (int t = 0; t < LSTM_T; ++t) {
    // 1. issue h-tile stage loads (system-coherent, bypass L1/L2 -> L3)
    const char* sp = gsb + ((t & 1) ? 262144 : 0);
    u32x4 s0, s1, s2, s3;
    asm volatile(
      "global_load_dwordx4 %0, %4, off sc0 sc1\n\t"
      "global_load_dwordx4 %1, %4, off offset:16 sc0 sc1\n\t"
      "global_load_dwordx4 %2, %4, off offset:32 sc0 sc1\n\t"
      "global_load_dwordx4 %3, %4, off offset:48 sc0 sc1"
      : "=v"(s0), "=v"(s1), "=v"(s2), "=v"(s3)
      : "v"(sp) : "memory");

    // 2. x-part MFMAs while stage loads are in flight
    f32x4 acc0 = {0.f, 0.f, 0.f, 0.f};   // Ah*Bh
    f32x4 acc1 = {0.f, 0.f, 0.f, 0.f};   // Ah*Bl
    f32x4 acc2 = {0.f, 0.f, 0.f, 0.f};   // Al*Bh
    asm volatile("s_nop 1" ::);          // VALU init -> MFMA srcC hazard pad
    #pragma unroll
    for (int ks = 0; ks < 4; ++ks) {
      MFMA16(acc0, xah[ks], bh[ks]);
      MFMA16(acc1, xah[ks], bl[ks]);
      MFMA16(acc2, xal[ks], bh[ks]);
    }

    // 3. land stage into swizzled LDS
    asm volatile("s_waitcnt vmcnt(0)" ::: "memory");
    *(u32x4*)(lwp + ((slin +  0) ^ smask)) = s0;
    *(u32x4*)(lwp + ((slin + 16) ^ smask)) = s1;
    *(u32x4*)(lwp + ((slin + 32) ^ smask)) = s2;
    *(u32x4*)(lwp + ((slin + 48) ^ smask)) = s3;
    __syncthreads();

    // 4. h-part MFMAs from LDS
    #pragma unroll
    for (int ks = 0; ks < 16; ++ks) {
      u32x4 ah = *(const u32x4*)(rbh + ((kg * 16 + ks * 64) ^ rms));
      u32x4 al = *(const u32x4*)(rbh + 16384 + ((kg * 16 + ks * 64) ^ rms));
      MFMA16(acc0, ah, bh[4 + ks]);
      MFMA16(acc1, ah, bl[4 + ks]);
      MFMA16(acc2, al, bh[4 + ks]);
    }
    asm volatile("s_nop 7\ns_nop 7\ns_nop 7" ::);   // MFMA -> VALU read pad
    #pragma unroll
    for (int r = 0; r < 4; ++r)
      zs[((w * 16) + (kg << 2) + r) * 16 + l15] = acc0[r] + acc1[r] + acc2[r];
    __syncthreads();

    // 5. prefetch next-step x fragments (hides under gates + barrier spin)
    if (t < 511) {
      #pragma unroll
      for (int ks = 0; ks < 4; ++ks) {
        xah[ks] = *(const u32x4*)(xbh + (size_t)(t + 1) * 32768 + ks * 32);
        xal[ks] = *(const u32x4*)(xbl + (size_t)(t + 1) * 32768 + ks * 32);
      }
    }

    // 6. gates: thread owns (gb, ug); z tiles: ntile = gate*2 + (uu>>4)
    const int ci = uu >> 4;
    const int cj = uu & 15;
    float zi = zs[(((0 + ci) * 16) + bb) * 16 + cj] + bi;
    float zf = zs[(((2 + ci) * 16) + bb) * 16 + cj] + bf_;
    float zg = zs[(((4 + ci) * 16) + bb) * 16 + cj] + bg;
    float zo = zs[(((6 + ci) * 16) + bb) * 16 + cj] + bo;
    float iv = 1.f / (1.f + __expf(-zi));
    float fv = 1.f / (1.f + __expf(-zf));
    float gv = tanh_fast(zg);
    float ov = 1.f / (1.f + __expf(-zo));
    c = fv * c + iv * gv;
    float hn = ov * tanh_fast(c);
    unsigned short hh16 = f2bf(hn);
    unsigned short hl16 = f2bf(hn - bf2f(hh16));
    {
      char* ph = (char*)(hwph + ((t & 1) ? 0 : 131072));   // write buffer (t+1)&1
      char* pl = (char*)(hwpl + ((t & 1) ? 0 : 131072));
      unsigned vh = hh16, vl = hl16;
      asm volatile(
        "global_store_short %0, %2, off sc0 sc1\n\t"
        "global_store_short %1, %3, off sc0 sc1"
        :: "v"(ph), "v"(pl), "v"(vh), "v"(vl) : "memory");
    }
    __builtin_nontemporal_store(hn, outp + (size_t)t * 512);
    if (t == 511) {
      // h_last at [67108864, +131072), c_last at [67239936, +131072)
      __builtin_nontemporal_store(hn, out + 67108864 + (size_t)gb * 512 + ug);
      __builtin_nontemporal_store(c,  out + 67239936 + (size_t)gb * 512 + ug);
    }

    // 7. group barrier: drain stores, relaxed atomic, coherent spin. No fences.
    asm volatile("s_waitcnt vmcnt(0)" ::: "memory");
    __syncthreads();
    if (tid == 0) {
      __hip_atomic_fetch_add(cnt, 1u, __ATOMIC_RELAXED, __HIP_MEMORY_SCOPE_AGENT);
      unsigned cur;
      do {
        asm volatile("global_load_dword %0, %1, off sc0 sc1\n\ts_waitcnt vmcnt(0)"
                     : "=v"(cur) : "v"(cnt) : "memory");
      } while (cur < target);
    }
    __syncthreads();
    target += 16;
  }
}

extern "C" void kernel_launch(void* const* d_in, const int* in_sizes, int n_in,
                              void* d_out, int out_size, void* d_ws, size_t ws_size,
                              hipStream_t stream) {
  const float* x    = (const float*)d_in[0];
  const float* W    = (const float*)d_in[1];
  const float* R    = (const float*)d_in[2];
  const float* bias = (const float*)d_in[3];
  float* out = (float*)d_out;
  char* ws = (char*)d_ws;

  unsigned*       counters = (unsigned*)ws;                       // 4 KB
  unsigned short* BTH = (unsigned short*)(ws + 4096);             // 2,621,440 B
  unsigned short* BTL = (unsigned short*)(ws + 2625536);          // 2,621,440 B
  unsigned short* XTH = (unsigned short*)(ws + 5246976);          // 33,554,432 B
  unsigned short* XTL = (unsigned short*)(ws + 38801408);         // 33,554,432 B
  unsigned short* HBH = (unsigned short*)(ws + 72355840);         // 524,288 B
  unsigned short* HBL = (unsigned short*)(ws + 72880128);         // 524,288 B

  hipMemsetAsync(counters, 0, 4096, stream);
  hipLaunchKernelGGL(xprep_kernel, dim3(16384), dim3(256), 0, stream, x, XTH, XTL);
  hipLaunchKernelGGL(wprep_kernel, dim3(2048), dim3(640), 0, stream, W, R, BTH, BTL);

  const unsigned short* XTHc = XTH;
  const unsigned short* XTLc = XTL;
  const unsigned short* BTHc = BTH;
  const unsigned short* BTLc = BTL;
  void* args[9];
  args[0] = (void*)&XTHc;
  args[1] = (void*)&XTLc;
  args[2] = (void*)&BTHc;
  args[3] = (void*)&BTLc;
  args[4] = (void*)&HBH;
  args[5] = (void*)&HBL;
  args[6] = (void*)&bias;
  args[7] = (void*)&out;
  args[8] = (void*)&counters;
  hipLaunchCooperativeKernel((void*)lstm_kernel, dim3(256), dim3(512), args, 0, stream);
}

// Round 9
// 2883.865 us; speedup vs baseline: 14.0621x; 1.1315x over previous
//
#include <hip/hip_runtime.h>
#include <stdint.h>

// LSTM B=256 T=512 F=128 U=512 (Keras LSTMCell: gates i,f,c,o; unit_forget_bias)
//
// R9 = R7 resubmitted verbatim (R7/R8 rounds were GPU-acquisition timeouts; never ran).
//
// R7 = R6 + fix for the asm-load hoist hazard (guide rule #18):
//   R6's deinterleave (register-only shifts/ors on p0..p3) was hoisted by the
//   compiler ABOVE the inline-asm `s_waitcnt vmcnt(0)` (memory clobber does not
//   order register-only ops; compiler doesn't track vmcnt of asm loads) ->
//   read in-flight load destinations -> NaN. Fix: sched_barrier(0) + opaque
//   "+v" touch of p0..p3 AFTER the waitcnt (asm volatile stays in order).
//   R5 was accidentally safe (direct LDS stores = memory ops can't cross).
//
// Structure (R6): per-block monotone flags (store h, drain, post t+2; consumers
// wave-poll 16 flags); packed u32 h exchange (hi16|lo16); coalesced stage +
// in-register deinterleave + swizzled conflict-free ds_write_b64; NT outputs
// after flag post; weights (160 VGPR) opaque-pinned; split-bf16 numerics
// z = Ah*Bh + Ah*Bl + Al*Bh (verified R4/R5).
// ws: flags 4KB | BTH | BTL | XTH | XTL | HP[2][256][512]u32  (~73.4 MB)

#define LSTM_T 512
#define LSTM_U 512

typedef float f32x4 __attribute__((ext_vector_type(4)));
typedef unsigned int u32x4 __attribute__((ext_vector_type(4)));
typedef unsigned int u32x2 __attribute__((ext_vector_type(2)));
typedef unsigned short u16x4 __attribute__((ext_vector_type(4)));

#define MFMA16(acc, va, vb) \
  asm volatile("v_mfma_f32_16x16x32_bf16 %0, %1, %2, %0" : "+v"(acc) : "v"(va), "v"(vb))

__device__ __forceinline__ unsigned short f2bf(float f) {
  unsigned u = __builtin_bit_cast(unsigned, f);
  u += 0x7fffu + ((u >> 16) & 1u);   // round-to-nearest-even
  return (unsigned short)(u >> 16);
}

__device__ __forceinline__ float bf2f(unsigned short h) {
  unsigned u = ((unsigned)h) << 16;
  return __builtin_bit_cast(float, u);
}

__device__ __forceinline__ float tanh_fast(float x) {
  float ax = fabsf(x);
  float e = __expf(-2.f * ax);
  float t = (1.f - e) / (1.f + e);
  return copysignf(t, x);
}

// x [B][T][F] fp32 -> XTH/XTL [T][B][F] bf16 hi/lo ; 4 elems/thread
__global__ void xprep_kernel(const float* __restrict__ x,
                             unsigned short* __restrict__ xth,
                             unsigned short* __restrict__ xtl) {
  unsigned i4 = blockIdx.x * 256 + threadIdx.x;
  const float* src = x + (size_t)i4 * 4;
  float a[4] = {src[0], src[1], src[2], src[3]};
  unsigned f4 = i4 & 31;
  unsigned t  = (i4 >> 5) & 511;
  unsigned b  = i4 >> 14;
  u16x4 oh, ol;
  #pragma unroll
  for (int j = 0; j < 4; ++j) {
    unsigned short hi = f2bf(a[j]);
    oh[j] = hi;
    ol[j] = f2bf(a[j] - bf2f(hi));
  }
  size_t off = (size_t)(t * 256 + b) * 128 + f4 * 4;
  *(u16x4*)(xth + off) = oh;
  *(u16x4*)(xtl + off) = ol;
}

// W [128][2048], R [512][2048] fp32 -> BTH/BTL [2048 cols][640 k] bf16 hi/lo
__global__ void wprep_kernel(const float* __restrict__ W, const float* __restrict__ R,
                             unsigned short* __restrict__ bth,
                             unsigned short* __restrict__ btl) {
  int col = blockIdx.x;
  int k   = threadIdx.x;
  float v = (k < 128) ? W[(size_t)k * 2048 + col] : R[(size_t)(k - 128) * 2048 + col];
  unsigned short hi = f2bf(v);
  float lo = v - bf2f(hi);
  bth[(size_t)col * 640 + k] = hi;
  btl[(size_t)col * 640 + k] = f2bf(lo);
}

__global__ __launch_bounds__(512, 1) void lstm_kernel(
    const unsigned short* __restrict__ xth,
    const unsigned short* __restrict__ xtl,
    const unsigned short* __restrict__ bth,
    const unsigned short* __restrict__ btl,
    unsigned* hp,                         // [2][256][512] u32 packed (hi16|lo16)
    const float* __restrict__ bias,       // [2048]
    float* __restrict__ out,              // [B*T*U | B*U | B*U] fp32
    unsigned* flags)                      // [256]: flags[g*16+idx], monotone
{
  const int tid = threadIdx.x;
  const int bid = blockIdx.x;
  const int g   = bid & 15;    // group (batch slice)
  const int idx = bid >> 4;    // unit slice within group
  const int u0  = idx << 5;    // 32 units per block

  const int lane = tid & 63;
  const int w    = tid >> 6;   // 8 waves
  const int l15  = lane & 15;
  const int kg   = lane >> 4;  // k-subgroup 0..3

  __shared__ float zs[2048];       // z tiles [ntile][row][col]
  __shared__ char  hlds[32768];    // [hi 16KB | lo 16KB], rows 1024B, chunk16^row swizzle

  // ---- preload t-invariant B fragments (160 VGPRs), defeat rematerialization ----
  const int colb = (w >> 1) * 512 + u0 + ((w & 1) << 4) + l15;  // global z-col
  u32x4 bh[20], bl[20];
  {
    const unsigned short* bp = bth + (size_t)colb * 640 + (kg << 3);
    const unsigned short* lp = btl + (size_t)colb * 640 + (kg << 3);
    #pragma unroll
    for (int ks = 0; ks < 20; ++ks) {
      bh[ks] = *(const u32x4*)(bp + ks * 32);
      bl[ks] = *(const u32x4*)(lp + ks * 32);
    }
  }
  #pragma unroll
  for (int ks = 0; ks < 20; ++ks)
    asm volatile("" : "+v"(bh[ks]), "+v"(bl[ks]));   // opaque def: no remat

  // ---- gate-phase constants ----
  const int bb = tid >> 5;           // 0..15
  const int uu = tid & 31;           // 0..31
  const int gb = g * 16 + bb;        // global batch
  const int ug = u0 + uu;            // global unit
  const float bi  = bias[ug];
  const float bf_ = bias[512 + ug];
  const float bg  = bias[1024 + ug];
  const float bo  = bias[1536 + ug];
  float c = 0.f;
  float* outp = out + (size_t)gb * (LSTM_T * LSTM_U) + ug;
  unsigned* hwp = hp + (size_t)gb * 512 + ug;        // + buf*131072

  // ---- x A-side bases ----
  const unsigned short* xbh = xth + (size_t)(g * 16 + l15) * 128 + (kg << 3);
  const unsigned short* xbl = xtl + (size_t)(g * 16 + l15) * 128 + (kg << 3);

  // ---- stage mapping: thread q stages rows rb+4j, chunk m>>1, half m&1 ----
  const int rb = tid >> 7;                 // 0..3
  const int m  = tid & 127;
  const unsigned* gsrc = hp + ((size_t)(g * 16 + rb) * 512 + m * 4);

  const unsigned* fpp = flags + g * 16 + l15;   // 16 flags per group, one 64B line
  unsigned* myflag = flags + g * 16 + idx;

  // ---- init: zero HP[0][gb][ug], drain, post flag=1 ----
  {
    unsigned z0 = 0;
    asm volatile("global_store_dword %0, %1, off sc0 sc1"
                 :: "v"(hp + (size_t)gb * 512 + ug), "v"(z0) : "memory");
    asm volatile("s_waitcnt vmcnt(0)" ::: "memory");
    __syncthreads();
    if (tid == 0) {
      unsigned one = 1;
      asm volatile("global_store_dword %0, %1, off sc0 sc1"
                   :: "v"(myflag), "v"(one) : "memory");
    }
  }

  for (int t = 0; t < LSTM_T; ++t) {
    // 1. poll group flags >= t+1 (all waves; 16 lanes replicated x4)
    {
      unsigned want = (unsigned)(t + 1);
      unsigned v;
      do {
        asm volatile("global_load_dword %0, %1, off sc0 sc1\n\ts_waitcnt vmcnt(0)"
                     : "=v"(v) : "v"(fpp) : "memory");
      } while (!__all((int)(v >= want)));
    }

    // 2. issue stage loads (packed h tile, coalesced 1KB/wave/load)
    const unsigned* sp = gsrc + ((t & 1) ? 131072 : 0);
    u32x4 p0, p1, p2, p3;
    asm volatile("global_load_dwordx4 %0, %1, off sc0 sc1"
                 : "=v"(p0) : "v"(sp) : "memory");
    asm volatile("global_load_dwordx4 %0, %1, off sc0 sc1"
                 : "=v"(p1) : "v"(sp + 2048) : "memory");
    asm volatile("global_load_dwordx4 %0, %1, off sc0 sc1"
                 : "=v"(p2) : "v"(sp + 4096) : "memory");
    asm volatile("global_load_dwordx4 %0, %1, off sc0 sc1"
                 : "=v"(p3) : "v"(sp + 6144) : "memory");

    // 3. x fragment loads for THIS step (compiler-tracked; drain handled below)
    u32x4 xah[4], xal[4];
    {
      const unsigned short* xh = xbh + (size_t)t * 32768;
      const unsigned short* xl = xbl + (size_t)t * 32768;
      #pragma unroll
      for (int ks = 0; ks < 4; ++ks) {
        xah[ks] = *(const u32x4*)(xh + ks * 32);
        xal[ks] = *(const u32x4*)(xl + ks * 32);
      }
    }

    // 4. drain stage loads, THEN deinterleave (rule #18: sched_barrier + opaque
    //    touch so the register-only unpack can't hoist above the waitcnt).
    asm volatile("s_waitcnt vmcnt(0)" ::: "memory");
    __builtin_amdgcn_sched_barrier(0);
    asm volatile("" : "+v"(p0), "+v"(p1), "+v"(p2), "+v"(p3));
    {
      #pragma unroll
      for (int j = 0; j < 4; ++j) {
        u32x4 p = (j == 0) ? p0 : (j == 1) ? p1 : (j == 2) ? p2 : p3;
        int r = rb + 4 * j;
        int base = r * 1024 + 16 * ((m >> 1) ^ (r & 15)) + (m & 1) * 8;
        u32x2 hi2, lo2;
        hi2[0] = (p[0] >> 16) | (p[1] & 0xffff0000u);
        hi2[1] = (p[2] >> 16) | (p[3] & 0xffff0000u);
        lo2[0] = (p[0] & 0xffffu) | (p[1] << 16);
        lo2[1] = (p[2] & 0xffffu) | (p[3] << 16);
        *(u32x2*)(hlds + base) = hi2;
        *(u32x2*)(hlds + 16384 + base) = lo2;
      }
    }

    // 5. x-part MFMAs (independent of LDS)
    f32x4 acc0 = {0.f, 0.f, 0.f, 0.f};   // Ah*Bh
    f32x4 acc1 = {0.f, 0.f, 0.f, 0.f};   // Ah*Bl
    f32x4 acc2 = {0.f, 0.f, 0.f, 0.f};   // Al*Bh
    asm volatile("s_nop 1" ::);
    #pragma unroll
    for (int ks = 0; ks < 4; ++ks) {
      MFMA16(acc0, xah[ks], bh[ks]);
      MFMA16(acc1, xah[ks], bl[ks]);
      MFMA16(acc2, xal[ks], bh[ks]);
    }
    __syncthreads();

    // 6. h-part MFMAs from LDS (2-way bank pattern = free)
    #pragma unroll
    for (int ks = 0; ks < 16; ++ks) {
      int off = l15 * 1024 + 16 * ((kg + 4 * ks) ^ l15);
      u32x4 ah = *(const u32x4*)(hlds + off);
      u32x4 al = *(const u32x4*)(hlds + 16384 + off);
      MFMA16(acc0, ah, bh[4 + ks]);
      MFMA16(acc1, ah, bl[4 + ks]);
      MFMA16(acc2, al, bh[4 + ks]);
    }
    asm volatile("s_nop 7\ns_nop 7\ns_nop 7" ::);
    #pragma unroll
    for (int r = 0; r < 4; ++r)
      zs[((w * 16) + (kg << 2) + r) * 16 + l15] = acc0[r] + acc1[r] + acc2[r];
    __syncthreads();

    // 7. gates: thread owns (gb, ug); z tiles: ntile = gate*2 + (uu>>4)
    const int ci = uu >> 4;
    const int cj = uu & 15;
    float zi = zs[(((0 + ci) * 16) + bb) * 16 + cj] + bi;
    float zf = zs[(((2 + ci) * 16) + bb) * 16 + cj] + bf_;
    float zg = zs[(((4 + ci) * 16) + bb) * 16 + cj] + bg;
    float zo = zs[(((6 + ci) * 16) + bb) * 16 + cj] + bo;
    float iv = 1.f / (1.f + __expf(-zi));
    float fv = 1.f / (1.f + __expf(-zf));
    float gv = tanh_fast(zg);
    float ov = 1.f / (1.f + __expf(-zo));
    c = fv * c + iv * gv;
    float hn = ov * tanh_fast(c);
    unsigned short hh16 = f2bf(hn);
    unsigned short hl16 = f2bf(hn - bf2f(hh16));
    unsigned packed = ((unsigned)hh16 << 16) | (unsigned)hl16;
    {
      unsigned* hdst = hwp + ((t & 1) ? 0 : 131072);   // write buffer (t+1)&1
      asm volatile("global_store_dword %0, %1, off sc0 sc1"
                   :: "v"(hdst), "v"(packed) : "memory");
    }
    asm volatile("s_waitcnt vmcnt(0)" ::: "memory");
    __syncthreads();
    if (tid == 0) {
      unsigned nf = (unsigned)(t + 2);
      asm volatile("global_store_dword %0, %1, off sc0 sc1"
                   :: "v"(myflag), "v"(nf) : "memory");
    }

    // 8. outputs AFTER flag post (HBM latency off the critical path)
    __builtin_nontemporal_store(hn, outp + (size_t)t * 512);
    if (t == 511) {
      __builtin_nontemporal_store(hn, out + 67108864 + (size_t)gb * 512 + ug);
      __builtin_nontemporal_store(c,  out + 67239936 + (size_t)gb * 512 + ug);
    }
  }
}

extern "C" void kernel_launch(void* const* d_in, const int* in_sizes, int n_in,
                              void* d_out, int out_size, void* d_ws, size_t ws_size,
                              hipStream_t stream) {
  const float* x    = (const float*)d_in[0];
  const float* W    = (const float*)d_in[1];
  const float* R    = (const float*)d_in[2];
  const float* bias = (const float*)d_in[3];
  float* out = (float*)d_out;
  char* ws = (char*)d_ws;

  unsigned*       flags = (unsigned*)ws;                          // 4 KB
  unsigned short* BTH = (unsigned short*)(ws + 4096);             // 2,621,440 B
  unsigned short* BTL = (unsigned short*)(ws + 2625536);          // 2,621,440 B
  unsigned short* XTH = (unsigned short*)(ws + 5246976);          // 33,554,432 B
  unsigned short* XTL = (unsigned short*)(ws + 38801408);         // 33,554,432 B
  unsigned*       HP  = (unsigned*)(ws + 72355840);               // 1,048,576 B

  hipMemsetAsync(flags, 0, 4096, stream);
  hipLaunchKernelGGL(xprep_kernel, dim3(16384), dim3(256), 0, stream, x, XTH, XTL);
  hipLaunchKernelGGL(wprep_kernel, dim3(2048), dim3(640), 0, stream, W, R, BTH, BTL);

  const unsigned short* XTHc = XTH;
  const unsigned short* XTLc = XTL;
  const unsigned short* BTHc = BTH;
  const unsigned short* BTLc = BTL;
  void* args[8];
  args[0] = (void*)&XTHc;
  args[1] = (void*)&XTLc;
  args[2] = (void*)&BTHc;
  args[3] = (void*)&BTLc;
  args[4] = (void*)&HP;
  args[5] = (void*)&bias;
  args[6] = (void*)&out;
  args[7] = (void*)&flags;
  hipLaunchCooperativeKernel((void*)lstm_kernel, dim3(256), dim3(512), args, 0, stream);
}